// Round 1
// baseline (837.584 us; speedup 1.0000x reference)
//
#include <hip/hip_runtime.h>

typedef unsigned short u16;
typedef unsigned int u32;
typedef u16 u16x8 __attribute__((ext_vector_type(8)));
typedef u16 u16x4 __attribute__((ext_vector_type(4)));
typedef float f32x4 __attribute__((ext_vector_type(4)));
typedef __bf16 bf16x8 __attribute__((ext_vector_type(8)));

#define NHEAD 12
#define NT 261
#define NGL 197
#define CDIM 768

__device__ __forceinline__ float bf2f(u16 u) {
    u32 x = ((u32)u) << 16;
    float f;
    __builtin_memcpy(&f, &x, 4);
    return f;
}
__device__ __forceinline__ u16 f2bf(float f) {
    u32 x;
    __builtin_memcpy(&x, &f, 4);
    x = (x + 0x7fffu + ((x >> 16) & 1u)) >> 16;
    return (u16)x;
}

// ---------------- fp32 -> bf16 weight conversion ----------------
__global__ __launch_bounds__(256) void convk(const float* __restrict__ in, u16* __restrict__ out, int n4) {
    int i = blockIdx.x * 256 + threadIdx.x;
    if (i >= n4) return;
    float4 v = ((const float4*)in)[i];
    u16x4 o;
    o[0] = f2bf(v.x); o[1] = f2bf(v.y); o[2] = f2bf(v.z); o[3] = f2bf(v.w);
    ((u16x4*)out)[i] = o;
}

// ---------------- LayerNorm (row of 768) -> bf16 ----------------
__global__ __launch_bounds__(256) void ln_k(const float* __restrict__ in, const float* __restrict__ w,
                                            const float* __restrict__ bia, u16* __restrict__ out) {
    int row = blockIdx.x;
    int tid = threadIdx.x;
    const float* r = in + (size_t)row * CDIM;
    float v0 = r[tid], v1 = r[tid + 256], v2 = r[tid + 512];
    float s = v0 + v1 + v2;
    float ss = v0 * v0 + v1 * v1 + v2 * v2;
#pragma unroll
    for (int off = 32; off; off >>= 1) {
        s += __shfl_xor(s, off);
        ss += __shfl_xor(ss, off);
    }
    __shared__ float ls[4], lss[4];
    int wv = tid >> 6;
    if ((tid & 63) == 0) { ls[wv] = s; lss[wv] = ss; }
    __syncthreads();
    s = ls[0] + ls[1] + ls[2] + ls[3];
    ss = lss[0] + lss[1] + lss[2] + lss[3];
    float mu = s * (1.f / 768.f);
    float var = ss * (1.f / 768.f) - mu * mu;
    float inv = rsqrtf(var + 1e-5f);
    u16* o = out + (size_t)row * CDIM;
    o[tid]       = f2bf((v0 - mu) * inv * w[tid]       + bia[tid]);
    o[tid + 256] = f2bf((v1 - mu) * inv * w[tid + 256] + bia[tid + 256]);
    o[tid + 512] = f2bf((v2 - mu) * inv * w[tid + 512] + bia[tid + 512]);
}

// ---------------- MFMA GEMM: C[m,n] = sum_k A[m,k]*B[n,k] (+epilogue) ----------------
// EPI: 0 = plain -> bf16 out; 1 = +bias +residual(fp32) -> fp32 out; 2 = +bias +gelu -> bf16 out
template <int EPI>
__global__ __launch_bounds__(256) void gemm_bt(const u16* __restrict__ A, const u16* __restrict__ Bw,
                                               int M, int N, int K,
                                               const float* __restrict__ bias,
                                               const float* __restrict__ resid, void* __restrict__ outp) {
    __shared__ __align__(16) u16 As[128 * 32];
    __shared__ __align__(16) u16 Bs[128 * 32];
    const int tid = threadIdx.x;
    const int bn = blockIdx.x, bm = blockIdx.y;
    const int lane = tid & 63, wv = tid >> 6;
    const int wr = wv >> 1, wc = wv & 1;
    const int l15 = lane & 15, lg = lane >> 4;
    f32x4 acc[4][4] = {};
    const int arow0 = bm * 128, brow0 = bn * 128;
    for (int k0 = 0; k0 < K; k0 += 32) {
#pragma unroll
        for (int i = 0; i < 2; ++i) {
            int c = i * 256 + tid;
            int row = c >> 2, kk = (c & 3) * 8;
            int ar = arow0 + row;
            if (ar >= M) ar = M - 1;
            *(u32*)0; // no-op placeholder removed below
        }
        // staging (separated for clarity)
#pragma unroll
        for (int i = 0; i < 2; ++i) {
            int c = i * 256 + tid;
            int row = c >> 2, kk = (c & 3) * 8;
            int ar = arow0 + row;
            if (ar >= M) ar = M - 1;
            *(uint4*)(As + row * 32 + kk) = *(const uint4*)(A + (size_t)ar * K + k0 + kk);
            *(uint4*)(Bs + row * 32 + kk) = *(const uint4*)(Bw + (size_t)(brow0 + row) * K + k0 + kk);
        }
        __syncthreads();
        bf16x8 af[4], bfr[4];
#pragma unroll
        for (int mi = 0; mi < 4; ++mi) af[mi] = *(const bf16x8*)(As + (wr * 64 + mi * 16 + l15) * 32 + lg * 8);
#pragma unroll
        for (int ni = 0; ni < 4; ++ni) bfr[ni] = *(const bf16x8*)(Bs + (wc * 64 + ni * 16 + l15) * 32 + lg * 8);
#pragma unroll
        for (int mi = 0; mi < 4; ++mi)
#pragma unroll
            for (int ni = 0; ni < 4; ++ni)
                acc[mi][ni] = __builtin_amdgcn_mfma_f32_16x16x32_bf16(af[mi], bfr[ni], acc[mi][ni], 0, 0, 0);
        __syncthreads();
    }
#pragma unroll
    for (int mi = 0; mi < 4; ++mi) {
        int row0 = arow0 + wr * 64 + mi * 16 + lg * 4;
#pragma unroll
        for (int ni = 0; ni < 4; ++ni) {
            int col = brow0 + wc * 64 + ni * 16 + l15;
            float bb = (EPI == 0) ? 0.f : bias[col];
#pragma unroll
            for (int r = 0; r < 4; ++r) {
                int row = row0 + r;
                if (row < M) {
                    float v = acc[mi][ni][r] + bb;
                    if (EPI == 2) v = 0.5f * v * (1.f + erff(v * 0.70710678118f));
                    if (EPI == 1) {
                        v += resid[(size_t)row * N + col];
                        ((float*)outp)[(size_t)row * N + col] = v;
                    } else {
                        ((u16*)outp)[(size_t)row * N + col] = f2bf(v);
                    }
                }
            }
        }
    }
}

// ---------------- Global attention (tokens 0..196), one wave per (b,h,q) ----------------
__global__ __launch_bounds__(64) void attn_global(const u16* __restrict__ qkv, u16* __restrict__ Z) {
    int bid = blockIdx.x;
    int q = bid % NGL;
    int bh = bid / NGL;
    int b = bh / NHEAD, h = bh % NHEAD;
    int lane = threadIdx.x;
    const u16* base = qkv + (size_t)b * NT * 2304 + h * 64;
    const u16* qrow = base + (size_t)q * 2304;
    float qv[64];
#pragma unroll
    for (int c = 0; c < 8; ++c) {
        u16x8 u = *(const u16x8*)(qrow + c * 8);
#pragma unroll
        for (int j = 0; j < 8; ++j) qv[c * 8 + j] = bf2f(u[j]);
    }
    float s[4];
#pragma unroll
    for (int j = 0; j < 4; ++j) {
        int key = lane + j * 64;
        if (key < NGL) {
            const u16* krow = base + 768 + (size_t)key * 2304;
            float acc = 0.f;
#pragma unroll
            for (int c = 0; c < 8; ++c) {
                u16x8 u = *(const u16x8*)(krow + c * 8);
#pragma unroll
                for (int jj = 0; jj < 8; ++jj) acc += qv[c * 8 + jj] * bf2f(u[jj]);
            }
            s[j] = acc * 0.125f;
        } else {
            s[j] = -1e30f;
        }
    }
    float mx = fmaxf(fmaxf(s[0], s[1]), fmaxf(s[2], s[3]));
#pragma unroll
    for (int off = 32; off; off >>= 1) mx = fmaxf(mx, __shfl_xor(mx, off));
    float e[4], sum = 0.f;
#pragma unroll
    for (int j = 0; j < 4; ++j) {
        e[j] = (lane + j * 64 < NGL) ? expf(s[j] - mx) : 0.f;
        sum += e[j];
    }
#pragma unroll
    for (int off = 32; off; off >>= 1) sum += __shfl_xor(sum, off);
    float inv = 1.f / sum;
    __shared__ float pl[256];
#pragma unroll
    for (int j = 0; j < 4; ++j) {
        int key = lane + j * 64;
        if (key < NGL) pl[key] = e[j] * inv;
    }
    __syncthreads();
    const u16* vbase = base + 1536;
    float o = 0.f;
#pragma unroll 4
    for (int k = 0; k < NGL; ++k) o += pl[k] * bf2f(vbase[(size_t)k * 2304 + lane]);
    Z[((size_t)b * NT + q) * CDIM + h * 64 + lane] = f2bf(o);
}

// ---------------- Neighborhood attention (point tokens), one wave per (b,m) ----------------
__global__ __launch_bounds__(64) void attn_neigh(const u16* __restrict__ qkv, const float* __restrict__ ps,
                                                 u16* __restrict__ Z) {
    int blk = blockIdx.x;
    int b = blk >> 6, m = blk & 63;
    int lane = threadIdx.x;
    float px = ps[((size_t)b * 64 + m) * 2 + 0] * (1.f / 16.f);
    float py = ps[((size_t)b * 64 + m) * 2 + 1] * (1.f / 16.f);
    int c0 = min(max((int)floorf(px), 0), 13);
    int c1 = min(max((int)ceilf(px), 0), 13);
    int r0 = min(max((int)floorf(py), 0), 13);
    int r1 = min(max((int)ceilf(py), 0), 13);
    int tok[4];
    tok[0] = 1 + r0 * 14 + c0;
    tok[1] = 1 + r1 * 14 + c0;
    tok[2] = 1 + r0 * 14 + c1;
    tok[3] = 1 + r1 * 14 + c1;
    const size_t rowq = ((size_t)b * NT + NGL + m) * 2304;
#pragma unroll 1
    for (int h = 0; h < NHEAD; ++h) {
        float qv = bf2f(qkv[rowq + h * 64 + lane]);
        float a[4];
#pragma unroll
        for (int j = 0; j < 4; ++j) {
            float p = qv * bf2f(qkv[((size_t)b * NT + tok[j]) * 2304 + 768 + h * 64 + lane]);
#pragma unroll
            for (int off = 32; off; off >>= 1) p += __shfl_xor(p, off);
            a[j] = p;
        }
        float mx = fmaxf(fmaxf(a[0], a[1]), fmaxf(a[2], a[3]));
        float e0 = expf(a[0] - mx), e1 = expf(a[1] - mx), e2 = expf(a[2] - mx), e3 = expf(a[3] - mx);
        float inv = 1.f / (e0 + e1 + e2 + e3);
        float v0 = bf2f(qkv[((size_t)b * NT + tok[0]) * 2304 + 1536 + h * 64 + lane]);
        float v1 = bf2f(qkv[((size_t)b * NT + tok[1]) * 2304 + 1536 + h * 64 + lane]);
        float v2 = bf2f(qkv[((size_t)b * NT + tok[2]) * 2304 + 1536 + h * 64 + lane]);
        float v3 = bf2f(qkv[((size_t)b * NT + tok[3]) * 2304 + 1536 + h * 64 + lane]);
        float o = (e0 * v0 + e1 * v1 + e2 * v2 + e3 * v3) * inv;
        Z[((size_t)b * NT + NGL + m) * CDIM + h * 64 + lane] = f2bf(o);
    }
}

extern "C" void kernel_launch(void* const* d_in, const int* in_sizes, int n_in,
                              void* d_out, int out_size, void* d_ws, size_t ws_size,
                              hipStream_t stream) {
    const float* x      = (const float*)d_in[0];
    const float* ps     = (const float*)d_in[1];
    const float* n1w    = (const float*)d_in[3];
    const float* n1b    = (const float*)d_in[4];
    const float* qkv_w  = (const float*)d_in[5];
    const float* proj_w = (const float*)d_in[6];
    const float* proj_b = (const float*)d_in[7];
    const float* n2w    = (const float*)d_in[8];
    const float* n2b    = (const float*)d_in[9];
    const float* fc1_w  = (const float*)d_in[10];
    const float* fc1_b  = (const float*)d_in[11];
    const float* fc2_w  = (const float*)d_in[12];
    const float* fc2_b  = (const float*)d_in[13];

    char* ws = (char*)d_ws;
    const int M = 32 * NT;  // 8352
    u16* hbuf  = (u16*)ws;                               // 12,828,672 B
    u16* qkvb  = (u16*)(ws + 12828672);                  // 38,486,016 B
    u16* Zb    = (u16*)(ws + 12828672 + 38486016);       // 12,828,672 B
    u16* Gb    = (u16*)(ws + 12828672);                  // 51,314,688 B (aliases qkv+Z, both dead)
    float* x1  = (float*)(ws + 64143360);                // 25,657,344 B
    u16* wq    = (u16*)(ws + 89800704);
    u16* wp    = wq + 2304 * 768;
    u16* w1    = wp + 768 * 768;
    u16* w2    = w1 + 3072 * 768;

    convk<<<(2304 * 768 / 4 + 255) / 256, 256, 0, stream>>>(qkv_w, wq, 2304 * 768 / 4);
    convk<<<(768 * 768 / 4 + 255) / 256, 256, 0, stream>>>(proj_w, wp, 768 * 768 / 4);
    convk<<<(3072 * 768 / 4 + 255) / 256, 256, 0, stream>>>(fc1_w, w1, 3072 * 768 / 4);
    convk<<<(768 * 3072 / 4 + 255) / 256, 256, 0, stream>>>(fc2_w, w2, 768 * 3072 / 4);

    ln_k<<<M, 256, 0, stream>>>(x, n1w, n1b, hbuf);
    gemm_bt<0><<<dim3(18, 66), 256, 0, stream>>>(hbuf, wq, M, 2304, 768, nullptr, nullptr, qkvb);
    attn_global<<<NGL * 32 * NHEAD, 64, 0, stream>>>(qkvb, Zb);
    attn_neigh<<<32 * 64, 64, 0, stream>>>(qkvb, ps, Zb);
    gemm_bt<1><<<dim3(6, 66), 256, 0, stream>>>(Zb, wp, M, 768, 768, proj_b, x, x1);
    ln_k<<<M, 256, 0, stream>>>(x1, n2w, n2b, hbuf);
    gemm_bt<2><<<dim3(24, 66), 256, 0, stream>>>(hbuf, w1, M, 3072, 768, fc1_b, nullptr, Gb);
    gemm_bt<1><<<dim3(6, 66), 256, 0, stream>>>(Gb, w2, M, 768, 3072, fc2_b, x1, (float*)d_out);
}

// Round 2
// 359.397 us; speedup vs baseline: 2.3305x; 2.3305x over previous
//
#include <hip/hip_runtime.h>

typedef unsigned short u16;
typedef unsigned int u32;
typedef u16 u16x8 __attribute__((ext_vector_type(8)));
typedef u16 u16x4 __attribute__((ext_vector_type(4)));
typedef float f32x4 __attribute__((ext_vector_type(4)));
typedef __bf16 bf16x8 __attribute__((ext_vector_type(8)));

#define NHEAD 12
#define NT 261
#define NGL 197
#define CDIM 768
#define KT 14            // 14 key tiles of 16 -> 224 padded keys
#define PS_STRIDE 232    // u16 units; 464 B rows -> 16B-aligned b128 reads, bank-spread
#define VT_STRIDE 232

__device__ __forceinline__ float bf2f(u16 u) {
    u32 x = ((u32)u) << 16;
    float f;
    __builtin_memcpy(&f, &x, 4);
    return f;
}
__device__ __forceinline__ u16 f2bf(float f) {
    u32 x;
    __builtin_memcpy(&x, &f, 4);
    x = (x + 0x7fffu + ((x >> 16) & 1u)) >> 16;
    return (u16)x;
}

#define GLD_LDS16(g, l) \
    __builtin_amdgcn_global_load_lds((const __attribute__((address_space(1))) void*)(g), \
                                     (__attribute__((address_space(3))) void*)(l), 16, 0, 0)

// ---------------- fp32 -> bf16 weight conversion ----------------
__global__ __launch_bounds__(256) void convk(const float* __restrict__ in, u16* __restrict__ out, int n4) {
    int i = blockIdx.x * 256 + threadIdx.x;
    if (i >= n4) return;
    float4 v = ((const float4*)in)[i];
    u16x4 o;
    o[0] = f2bf(v.x); o[1] = f2bf(v.y); o[2] = f2bf(v.z); o[3] = f2bf(v.w);
    ((u16x4*)out)[i] = o;
}

// ---------------- LayerNorm (row of 768) -> bf16 ----------------
__global__ __launch_bounds__(256) void ln_k(const float* __restrict__ in, const float* __restrict__ w,
                                            const float* __restrict__ bia, u16* __restrict__ out) {
    int row = blockIdx.x;
    int tid = threadIdx.x;
    const float* r = in + (size_t)row * CDIM;
    float v0 = r[tid], v1 = r[tid + 256], v2 = r[tid + 512];
    float s = v0 + v1 + v2;
    float ss = v0 * v0 + v1 * v1 + v2 * v2;
#pragma unroll
    for (int off = 32; off; off >>= 1) {
        s += __shfl_xor(s, off);
        ss += __shfl_xor(ss, off);
    }
    __shared__ float ls[4], lss[4];
    int wv = tid >> 6;
    if ((tid & 63) == 0) { ls[wv] = s; lss[wv] = ss; }
    __syncthreads();
    s = ls[0] + ls[1] + ls[2] + ls[3];
    ss = lss[0] + lss[1] + lss[2] + lss[3];
    float mu = s * (1.f / 768.f);
    float var = ss * (1.f / 768.f) - mu * mu;
    float inv = rsqrtf(var + 1e-5f);
    u16* o = out + (size_t)row * CDIM;
    o[tid]       = f2bf((v0 - mu) * inv * w[tid]       + bia[tid]);
    o[tid + 256] = f2bf((v1 - mu) * inv * w[tid + 256] + bia[tid + 256]);
    o[tid + 512] = f2bf((v2 - mu) * inv * w[tid + 512] + bia[tid + 512]);
}

// ---------------- MFMA GEMM: C[m,n] = sum_k A[m,k]*B[n,k] (+epilogue) ----------------
// EPI: 0 = plain -> bf16 out; 1 = +bias +residual(fp32) -> fp32 out; 2 = +bias +gelu -> bf16 out
template <int EPI>
__global__ __launch_bounds__(256) void gemm_bt(const u16* __restrict__ A, const u16* __restrict__ Bw,
                                               int M, int N, int K,
                                               const float* __restrict__ bias,
                                               const float* __restrict__ resid, void* __restrict__ outp) {
    __shared__ __align__(16) u16 As[128 * 32];
    __shared__ __align__(16) u16 Bs[128 * 32];
    const int tid = threadIdx.x;
    const int bn = blockIdx.x, bm = blockIdx.y;
    const int lane = tid & 63, wv = tid >> 6;
    const int wr = wv >> 1, wc = wv & 1;
    const int l15 = lane & 15, lg = lane >> 4;
    f32x4 acc[4][4] = {};
    const int arow0 = bm * 128, brow0 = bn * 128;
    const int srow = tid >> 2, skk = (tid & 3) * 8;   // per-thread staging coords (i=0: rows 0..63)
    int ar0 = arow0 + srow;        if (ar0 >= M) ar0 = M - 1;
    int ar1 = arow0 + srow + 64;   if (ar1 >= M) ar1 = M - 1;
    const u16* gA0 = A + (size_t)ar0 * K + skk;
    const u16* gA1 = A + (size_t)ar1 * K + skk;
    const u16* gB0 = Bw + (size_t)(brow0 + srow) * K + skk;
    const u16* gB1 = Bw + (size_t)(brow0 + srow + 64) * K + skk;
    u16* lA0 = As + srow * 32 + skk;
    u16* lA1 = As + (srow + 64) * 32 + skk;
    u16* lB0 = Bs + srow * 32 + skk;
    u16* lB1 = Bs + (srow + 64) * 32 + skk;
    for (int k0 = 0; k0 < K; k0 += 32) {
        GLD_LDS16(gA0 + k0, lA0);
        GLD_LDS16(gA1 + k0, lA1);
        GLD_LDS16(gB0 + k0, lB0);
        GLD_LDS16(gB1 + k0, lB1);
        __syncthreads();
        bf16x8 af[4], bfr[4];
#pragma unroll
        for (int mi = 0; mi < 4; ++mi) af[mi] = *(const bf16x8*)(As + (wr * 64 + mi * 16 + l15) * 32 + lg * 8);
#pragma unroll
        for (int ni = 0; ni < 4; ++ni) bfr[ni] = *(const bf16x8*)(Bs + (wc * 64 + ni * 16 + l15) * 32 + lg * 8);
#pragma unroll
        for (int mi = 0; mi < 4; ++mi)
#pragma unroll
            for (int ni = 0; ni < 4; ++ni)
                acc[mi][ni] = __builtin_amdgcn_mfma_f32_16x16x32_bf16(af[mi], bfr[ni], acc[mi][ni], 0, 0, 0);
        __syncthreads();
    }
#pragma unroll
    for (int mi = 0; mi < 4; ++mi) {
        int row0 = arow0 + wr * 64 + mi * 16 + lg * 4;
#pragma unroll
        for (int ni = 0; ni < 4; ++ni) {
            int col = brow0 + wc * 64 + ni * 16 + l15;
            float bb = (EPI == 0) ? 0.f : bias[col];
#pragma unroll
            for (int r = 0; r < 4; ++r) {
                int row = row0 + r;
                if (row < M) {
                    float v = acc[mi][ni][r] + bb;
                    if (EPI == 2) v = 0.5f * v * (1.f + erff(v * 0.70710678118f));
                    if (EPI == 1) {
                        v += resid[(size_t)row * N + col];
                        ((float*)outp)[(size_t)row * N + col] = v;
                    } else {
                        ((u16*)outp)[(size_t)row * N + col] = f2bf(v);
                    }
                }
            }
        }
    }
}

// ---------------- Global attention via MFMA ----------------
// grid: (b,h,qt) = 32*12*4 blocks of 256 threads; each wave owns 16 query rows.
// LDS: region0 = K swizzled [224 rows][64 bf16] (28672 B), reused as P [4 waves][16][PS_STRIDE]
//      region1 = V transposed [64 d][VT_STRIDE] (data cols = 224 keys)
__global__ __launch_bounds__(256) void attn_global_mfma(const u16* __restrict__ qkv, u16* __restrict__ Z) {
    __shared__ __align__(16) u16 lds0[4 * 16 * PS_STRIDE];   // 29696 B (>= 28672 for K)
    __shared__ __align__(16) u16 Vt[64 * VT_STRIDE];         // 29696 B
    const int tid = threadIdx.x;
    const int blk = blockIdx.x;
    const int qt = blk & 3;
    const int bh = blk >> 2;
    const int h = bh % NHEAD, b = bh / NHEAD;
    const int lane = tid & 63, wv = tid >> 6;
    const int l15 = lane & 15, lg = lane >> 4;
    const u16* base = qkv + (size_t)b * NT * 2304;

    // stage K (XOR-swizzled rows), zero pad rows >= 197
    for (int c = tid; c < 224 * 8; c += 256) {
        int row = c >> 3, ch = c & 7;
        u16x8 v = {};
        if (row < NGL) v = *(const u16x8*)(base + (size_t)row * 2304 + 768 + h * 64 + ch * 8);
        int byte = row * 128 + ((ch * 16) ^ ((row & 7) << 4));
        *(u16x8*)((char*)lds0 + byte) = v;
    }
    // stage V transposed: Vt[d][m], zero pad cols m >= 197
    for (int c = tid; c < 112 * 8; c += 256) {
        int mp = c >> 3, dch = c & 7;
        int m0 = mp * 2;
        u16x8 a0 = {}, a1 = {};
        if (m0 < NGL)     a0 = *(const u16x8*)(base + (size_t)m0 * 2304 + 1536 + h * 64 + dch * 8);
        if (m0 + 1 < NGL) a1 = *(const u16x8*)(base + (size_t)(m0 + 1) * 2304 + 1536 + h * 64 + dch * 8);
#pragma unroll
        for (int j = 0; j < 8; ++j) {
            u32 pk = (u32)a0[j] | ((u32)a1[j] << 16);
            *(u32*)((char*)Vt + (size_t)(dch * 8 + j) * (VT_STRIDE * 2) + m0 * 2) = pk;
        }
    }
    // Q fragments from global (16 rows per wave)
    const int q0 = qt * 64 + wv * 16;
    int qrow = q0 + l15; if (qrow > NGL - 1) qrow = NGL - 1;
    bf16x8 aq0 = *(const bf16x8*)(base + (size_t)qrow * 2304 + h * 64 + lg * 8);
    bf16x8 aq1 = *(const bf16x8*)(base + (size_t)qrow * 2304 + h * 64 + 32 + lg * 8);
    __syncthreads();

    // S = Q K^T * scale ; C/D layout: col(l15)=key, row(4*lg+r)=query
    f32x4 s[KT];
    const int sw = (l15 & 7) << 4;
#pragma unroll
    for (int t = 0; t < KT; ++t) {
        const char* krow = (const char*)lds0 + (t * 16 + l15) * 128;
        bf16x8 bk0 = *(const bf16x8*)(krow + ((lg * 16) ^ sw));
        bf16x8 bk1 = *(const bf16x8*)(krow + ((64 + lg * 16) ^ sw));
        f32x4 acc = {};
        acc = __builtin_amdgcn_mfma_f32_16x16x32_bf16(aq0, bk0, acc, 0, 0, 0);
        acc = __builtin_amdgcn_mfma_f32_16x16x32_bf16(aq1, bk1, acc, 0, 0, 0);
        s[t] = acc * 0.125f;
    }
    // softmax over keys: reduce across the 16-lane group (l15) and tiles
    float mx[4] = {-1e30f, -1e30f, -1e30f, -1e30f};
#pragma unroll
    for (int t = 0; t < KT; ++t)
#pragma unroll
        for (int r = 0; r < 4; ++r) mx[r] = fmaxf(mx[r], s[t][r]);
#pragma unroll
    for (int off = 1; off < 16; off <<= 1)
#pragma unroll
        for (int r = 0; r < 4; ++r) mx[r] = fmaxf(mx[r], __shfl_xor(mx[r], off));
    float sum[4] = {};
#pragma unroll
    for (int t = 0; t < KT; ++t) {
        bool valid = (t * 16 + l15) < NGL;
#pragma unroll
        for (int r = 0; r < 4; ++r) {
            float e = valid ? __expf(s[t][r] - mx[r]) : 0.f;
            s[t][r] = e;
            sum[r] += e;
        }
    }
#pragma unroll
    for (int off = 1; off < 16; off <<= 1)
#pragma unroll
        for (int r = 0; r < 4; ++r) sum[r] += __shfl_xor(sum[r], off);
    float inv[4];
#pragma unroll
    for (int r = 0; r < 4; ++r) inv[r] = 1.f / sum[r];

    __syncthreads();   // all waves done reading K; reuse lds0 as P
    u16* Pw = lds0 + wv * 16 * PS_STRIDE;
#pragma unroll
    for (int t = 0; t < KT; ++t)
#pragma unroll
        for (int r = 0; r < 4; ++r)
            Pw[(4 * lg + r) * PS_STRIDE + t * 16 + l15] = f2bf(s[t][r] * inv[r]);

    // O = P V : A-frag rows = queries (l15), contiguous keys; B-frag = Vt rows d (l15)
    f32x4 o[4] = {};
#pragma unroll
    for (int ks = 0; ks < 7; ++ks) {
        bf16x8 pa = *(const bf16x8*)(Pw + l15 * PS_STRIDE + ks * 32 + lg * 8);
#pragma unroll
        for (int dt = 0; dt < 4; ++dt) {
            bf16x8 bv = *(const bf16x8*)((const char*)Vt + (size_t)(dt * 16 + l15) * (VT_STRIDE * 2) + ks * 64 + lg * 16);
            o[dt] = __builtin_amdgcn_mfma_f32_16x16x32_bf16(pa, bv, o[dt], 0, 0, 0);
        }
    }
#pragma unroll
    for (int dt = 0; dt < 4; ++dt)
#pragma unroll
        for (int r = 0; r < 4; ++r) {
            int q = q0 + 4 * lg + r;
            if (q < NGL) Z[((size_t)b * NT + q) * CDIM + h * 64 + dt * 16 + l15] = f2bf(o[dt][r]);
        }
}

// ---------------- Neighborhood attention (point tokens), one wave per (b,m) ----------------
__global__ __launch_bounds__(64) void attn_neigh(const u16* __restrict__ qkv, const float* __restrict__ ps,
                                                 u16* __restrict__ Z) {
    int blk = blockIdx.x;
    int b = blk >> 6, m = blk & 63;
    int lane = threadIdx.x;
    float px = ps[((size_t)b * 64 + m) * 2 + 0] * (1.f / 16.f);
    float py = ps[((size_t)b * 64 + m) * 2 + 1] * (1.f / 16.f);
    int c0 = min(max((int)floorf(px), 0), 13);
    int c1 = min(max((int)ceilf(px), 0), 13);
    int r0 = min(max((int)floorf(py), 0), 13);
    int r1 = min(max((int)ceilf(py), 0), 13);
    int tok[4];
    tok[0] = 1 + r0 * 14 + c0;
    tok[1] = 1 + r1 * 14 + c0;
    tok[2] = 1 + r0 * 14 + c1;
    tok[3] = 1 + r1 * 14 + c1;
    const size_t rowq = ((size_t)b * NT + NGL + m) * 2304;
#pragma unroll 1
    for (int h = 0; h < NHEAD; ++h) {
        float qv = bf2f(qkv[rowq + h * 64 + lane]);
        float a[4];
#pragma unroll
        for (int j = 0; j < 4; ++j) {
            float p = qv * bf2f(qkv[((size_t)b * NT + tok[j]) * 2304 + 768 + h * 64 + lane]);
#pragma unroll
            for (int off = 32; off; off >>= 1) p += __shfl_xor(p, off);
            a[j] = p;
        }
        float mx = fmaxf(fmaxf(a[0], a[1]), fmaxf(a[2], a[3]));
        float e0 = expf(a[0] - mx), e1 = expf(a[1] - mx), e2 = expf(a[2] - mx), e3 = expf(a[3] - mx);
        float inv = 1.f / (e0 + e1 + e2 + e3);
        float v0 = bf2f(qkv[((size_t)b * NT + tok[0]) * 2304 + 1536 + h * 64 + lane]);
        float v1 = bf2f(qkv[((size_t)b * NT + tok[1]) * 2304 + 1536 + h * 64 + lane]);
        float v2 = bf2f(qkv[((size_t)b * NT + tok[2]) * 2304 + 1536 + h * 64 + lane]);
        float v3 = bf2f(qkv[((size_t)b * NT + tok[3]) * 2304 + 1536 + h * 64 + lane]);
        float o = (e0 * v0 + e1 * v1 + e2 * v2 + e3 * v3) * inv;
        Z[((size_t)b * NT + NGL + m) * CDIM + h * 64 + lane] = f2bf(o);
    }
}

extern "C" void kernel_launch(void* const* d_in, const int* in_sizes, int n_in,
                              void* d_out, int out_size, void* d_ws, size_t ws_size,
                              hipStream_t stream) {
    const float* x      = (const float*)d_in[0];
    const float* ps     = (const float*)d_in[1];
    const float* n1w    = (const float*)d_in[3];
    const float* n1b    = (const float*)d_in[4];
    const float* qkv_w  = (const float*)d_in[5];
    const float* proj_w = (const float*)d_in[6];
    const float* proj_b = (const float*)d_in[7];
    const float* n2w    = (const float*)d_in[8];
    const float* n2b    = (const float*)d_in[9];
    const float* fc1_w  = (const float*)d_in[10];
    const float* fc1_b  = (const float*)d_in[11];
    const float* fc2_w  = (const float*)d_in[12];
    const float* fc2_b  = (const float*)d_in[13];

    char* ws = (char*)d_ws;
    const int M = 32 * NT;  // 8352
    u16* hbuf  = (u16*)ws;                               // 12,828,672 B
    u16* qkvb  = (u16*)(ws + 12828672);                  // 38,486,016 B
    u16* Zb    = (u16*)(ws + 12828672 + 38486016);       // 12,828,672 B
    u16* Gb    = (u16*)(ws + 12828672);                  // 51,314,688 B (aliases qkv+Z, both dead)
    float* x1  = (float*)(ws + 64143360);                // 25,657,344 B
    u16* wq    = (u16*)(ws + 89800704);
    u16* wp    = wq + 2304 * 768;
    u16* w1    = wp + 768 * 768;
    u16* w2    = w1 + 3072 * 768;

    convk<<<(2304 * 768 / 4 + 255) / 256, 256, 0, stream>>>(qkv_w, wq, 2304 * 768 / 4);
    convk<<<(768 * 768 / 4 + 255) / 256, 256, 0, stream>>>(proj_w, wp, 768 * 768 / 4);
    convk<<<(3072 * 768 / 4 + 255) / 256, 256, 0, stream>>>(fc1_w, w1, 3072 * 768 / 4);
    convk<<<(768 * 3072 / 4 + 255) / 256, 256, 0, stream>>>(fc2_w, w2, 768 * 3072 / 4);

    ln_k<<<M, 256, 0, stream>>>(x, n1w, n1b, hbuf);
    gemm_bt<0><<<dim3(18, 66), 256, 0, stream>>>(hbuf, wq, M, 2304, 768, nullptr, nullptr, qkvb);
    attn_global_mfma<<<32 * NHEAD * 4, 256, 0, stream>>>(qkvb, Zb);
    attn_neigh<<<32 * 64, 64, 0, stream>>>(qkvb, ps, Zb);
    gemm_bt<1><<<dim3(6, 66), 256, 0, stream>>>(Zb, wp, M, 768, 768, proj_b, x, x1);
    ln_k<<<M, 256, 0, stream>>>(x1, n2w, n2b, hbuf);
    gemm_bt<2><<<dim3(24, 66), 256, 0, stream>>>(hbuf, w1, M, 3072, 768, fc1_b, nullptr, Gb);
    gemm_bt<1><<<dim3(6, 66), 256, 0, stream>>>(Gb, w2, M, 768, 3072, fc2_b, x1, (float*)d_out);
}

// Round 3
// 308.017 us; speedup vs baseline: 2.7193x; 1.1668x over previous
//
#include <hip/hip_runtime.h>

typedef unsigned short u16;
typedef unsigned int u32;
typedef u16 u16x8 __attribute__((ext_vector_type(8)));
typedef u16 u16x4 __attribute__((ext_vector_type(4)));
typedef float f32x4 __attribute__((ext_vector_type(4)));
typedef __bf16 bf16x8 __attribute__((ext_vector_type(8)));

#define NHEAD 12
#define NT 261
#define NGL 197
#define CDIM 768
#define KT 14
#define PS_STRIDE 232
#define VT_STRIDE 232

__device__ __forceinline__ float bf2f(u16 u) {
    u32 x = ((u32)u) << 16;
    float f;
    __builtin_memcpy(&f, &x, 4);
    return f;
}
__device__ __forceinline__ u16 f2bf(float f) {
    u32 x;
    __builtin_memcpy(&x, &f, 4);
    x = (x + 0x7fffu + ((x >> 16) & 1u)) >> 16;
    return (u16)x;
}

#define GLD_LDS16(g, l) \
    __builtin_amdgcn_global_load_lds((const __attribute__((address_space(1))) void*)(g), \
                                     (__attribute__((address_space(3))) void*)(l), 16, 0, 0)
#define WAITV(n) asm volatile("s_waitcnt vmcnt(" #n ")" ::: "memory")
#define BAR() __builtin_amdgcn_s_barrier()

// ---------------- fp32 -> bf16 weight conversion ----------------
__global__ __launch_bounds__(256) void convk(const float* __restrict__ in, u16* __restrict__ out, int n4) {
    int i = blockIdx.x * 256 + threadIdx.x;
    if (i >= n4) return;
    float4 v = ((const float4*)in)[i];
    u16x4 o;
    o[0] = f2bf(v.x); o[1] = f2bf(v.y); o[2] = f2bf(v.z); o[3] = f2bf(v.w);
    ((u16x4*)out)[i] = o;
}

// ---------------- LayerNorm (row of 768) -> bf16 ----------------
__global__ __launch_bounds__(256) void ln_k(const float* __restrict__ in, const float* __restrict__ w,
                                            const float* __restrict__ bia, u16* __restrict__ out) {
    int row = blockIdx.x;
    int tid = threadIdx.x;
    const float* r = in + (size_t)row * CDIM;
    float v0 = r[tid], v1 = r[tid + 256], v2 = r[tid + 512];
    float s = v0 + v1 + v2;
    float ss = v0 * v0 + v1 * v1 + v2 * v2;
#pragma unroll
    for (int off = 32; off; off >>= 1) {
        s += __shfl_xor(s, off);
        ss += __shfl_xor(ss, off);
    }
    __shared__ float ls[4], lss[4];
    int wv = tid >> 6;
    if ((tid & 63) == 0) { ls[wv] = s; lss[wv] = ss; }
    __syncthreads();
    s = ls[0] + ls[1] + ls[2] + ls[3];
    ss = lss[0] + lss[1] + lss[2] + lss[3];
    float mu = s * (1.f / 768.f);
    float var = ss * (1.f / 768.f) - mu * mu;
    float inv = rsqrtf(var + 1e-5f);
    u16* o = out + (size_t)row * CDIM;
    o[tid]       = f2bf((v0 - mu) * inv * w[tid]       + bia[tid]);
    o[tid + 256] = f2bf((v1 - mu) * inv * w[tid + 256] + bia[tid + 256]);
    o[tid + 512] = f2bf((v2 - mu) * inv * w[tid + 512] + bia[tid + 512]);
}

// ---------------- double-buffered MFMA GEMM: C[m,n] = sum_k A[m,k]*B[n,k] ----------------
// BM=BN=128, BK=64, 256 threads (2x2 waves, 64x64 per wave). nt = K/64 (>=2).
// LDS linear dest for global_load_lds; XOR swizzle via pre-swizzled global source (rule #21).
// EPI: 0 = plain -> bf16; 1 = +bias +residual(fp32) -> fp32; 2 = +bias +gelu -> bf16
template <int EPI>
__global__ __launch_bounds__(256, 2) void gemm2(const u16* __restrict__ A, const u16* __restrict__ Bw,
                                                int M, int N, int K, int nbn,
                                                const float* __restrict__ bias,
                                                const float* __restrict__ resid, void* __restrict__ outp) {
    __shared__ __align__(16) u16 sm[2][2][128 * 64];   // [buf][A/B][tile] = 64 KiB
    const int tid = threadIdx.x;
    // bijective XCD swizzle (m204): contiguous chunk of blocks per XCD
    const int nwg = gridDim.x;
    const int q = nwg >> 3, r = nwg & 7;
    const int xcd = blockIdx.x & 7, within = blockIdx.x >> 3;
    const int id2 = (xcd < r ? xcd * (q + 1) : r * (q + 1) + (xcd - r) * q) + within;
    const int bm = id2 / nbn, bn = id2 % nbn;
    const int lane = tid & 63, wv = tid >> 6;
    const int wr = wv >> 1, wc = wv & 1;
    const int l15 = lane & 15, lg = lane >> 4;
    const int arow0 = bm * 128, brow0 = bn * 128;
    const int nt = K >> 6;

    // staging addresses: 4 issues x 16B per thread per operand tile
    const u16* gA[4];
    const u16* gB[4];
#pragma unroll
    for (int i = 0; i < 4; ++i) {
        int off = i * 4096 + tid * 16;                      // byte offset in [128][128B] tile
        int row = off >> 7;
        int colb = (off & 127) ^ ((row & 7) << 4);          // inverse swizzle on source
        int ar = arow0 + row; if (ar >= M) ar = M - 1;
        gA[i] = A + (size_t)ar * K + (colb >> 1);
        gB[i] = Bw + (size_t)(brow0 + row) * K + (colb >> 1);
    }
    const int ldso = tid * 8;                               // u16: linear lane*16B

    f32x4 acc[4][4] = {};
    const int swz = (l15 & 7) << 3;                         // u16-unit XOR for frag reads

    // prologue: stage tiles 0 and 1
#pragma unroll
    for (int i = 0; i < 4; ++i) GLD_LDS16(gA[i], &sm[0][0][i * 2048 + ldso]);
#pragma unroll
    for (int i = 0; i < 4; ++i) GLD_LDS16(gB[i], &sm[0][1][i * 2048 + ldso]);
#pragma unroll
    for (int i = 0; i < 4; ++i) GLD_LDS16(gA[i] + 64, &sm[1][0][i * 2048 + ldso]);
#pragma unroll
    for (int i = 0; i < 4; ++i) GLD_LDS16(gB[i] + 64, &sm[1][1][i * 2048 + ldso]);
    WAITV(8);
    BAR();

    for (int t = 0; t < nt; ++t) {
        const int cur = t & 1;
        const u16* As_ = &sm[cur][0][0];
        const u16* Bs_ = &sm[cur][1][0];
#pragma unroll
        for (int h = 0; h < 2; ++h) {
            bf16x8 af[4], bfr[4];
#pragma unroll
            for (int mi = 0; mi < 4; ++mi)
                af[mi] = *(const bf16x8*)(As_ + (wr * 64 + mi * 16 + l15) * 64 + ((h * 32 + lg * 8) ^ swz));
#pragma unroll
            for (int ni = 0; ni < 4; ++ni)
                bfr[ni] = *(const bf16x8*)(Bs_ + (wc * 64 + ni * 16 + l15) * 64 + ((h * 32 + lg * 8) ^ swz));
#pragma unroll
            for (int mi = 0; mi < 4; ++mi)
#pragma unroll
                for (int ni = 0; ni < 4; ++ni)
                    acc[mi][ni] = __builtin_amdgcn_mfma_f32_16x16x32_bf16(af[mi], bfr[ni], acc[mi][ni], 0, 0, 0);
        }
        if (t + 1 < nt) {
            BAR();                                          // all waves done reading buf[cur]
            if (t + 2 < nt) {
                const size_t ko = (size_t)(t + 2) * 64;
#pragma unroll
                for (int i = 0; i < 4; ++i) GLD_LDS16(gA[i] + ko, &sm[cur][0][i * 2048 + ldso]);
#pragma unroll
                for (int i = 0; i < 4; ++i) GLD_LDS16(gB[i] + ko, &sm[cur][1][i * 2048 + ldso]);
                WAITV(8);                                   // tile t+1 landed; keep new 8 in flight
            } else {
                WAITV(0);
            }
            BAR();                                          // buf[cur^1] visible to all waves
        }
    }

#pragma unroll
    for (int mi = 0; mi < 4; ++mi) {
        int row0 = arow0 + wr * 64 + mi * 16 + lg * 4;
#pragma unroll
        for (int ni = 0; ni < 4; ++ni) {
            int col = brow0 + wc * 64 + ni * 16 + l15;
            float bb = (EPI == 0) ? 0.f : bias[col];
#pragma unroll
            for (int rr = 0; rr < 4; ++rr) {
                int row = row0 + rr;
                if (row < M) {
                    float v = acc[mi][ni][rr] + bb;
                    if (EPI == 2) v = 0.5f * v * (1.f + erff(v * 0.70710678118f));
                    if (EPI == 1) {
                        v += resid[(size_t)row * N + col];
                        ((float*)outp)[(size_t)row * N + col] = v;
                    } else {
                        ((u16*)outp)[(size_t)row * N + col] = f2bf(v);
                    }
                }
            }
        }
    }
}

// ---------------- Global attention via MFMA ----------------
__global__ __launch_bounds__(256) void attn_global_mfma(const u16* __restrict__ qkv, u16* __restrict__ Z) {
    __shared__ __align__(16) u16 lds0[4 * 16 * PS_STRIDE];
    __shared__ __align__(16) u16 Vt[64 * VT_STRIDE];
    const int tid = threadIdx.x;
    const int blk = blockIdx.x;
    const int qt = blk & 3;
    const int bh = blk >> 2;
    const int h = bh % NHEAD, b = bh / NHEAD;
    const int lane = tid & 63, wv = tid >> 6;
    const int l15 = lane & 15, lg = lane >> 4;
    const u16* base = qkv + (size_t)b * NT * 2304;

    for (int c = tid; c < 224 * 8; c += 256) {
        int row = c >> 3, ch = c & 7;
        u16x8 v = {};
        if (row < NGL) v = *(const u16x8*)(base + (size_t)row * 2304 + 768 + h * 64 + ch * 8);
        int byte = row * 128 + ((ch * 16) ^ ((row & 7) << 4));
        *(u16x8*)((char*)lds0 + byte) = v;
    }
    for (int c = tid; c < 112 * 8; c += 256) {
        int mp = c >> 3, dch = c & 7;
        int m0 = mp * 2;
        u16x8 a0 = {}, a1 = {};
        if (m0 < NGL)     a0 = *(const u16x8*)(base + (size_t)m0 * 2304 + 1536 + h * 64 + dch * 8);
        if (m0 + 1 < NGL) a1 = *(const u16x8*)(base + (size_t)(m0 + 1) * 2304 + 1536 + h * 64 + dch * 8);
#pragma unroll
        for (int j = 0; j < 8; ++j) {
            u32 pk = (u32)a0[j] | ((u32)a1[j] << 16);
            *(u32*)((char*)Vt + (size_t)(dch * 8 + j) * (VT_STRIDE * 2) + m0 * 2) = pk;
        }
    }
    const int q0 = qt * 64 + wv * 16;
    int qrow = q0 + l15; if (qrow > NGL - 1) qrow = NGL - 1;
    bf16x8 aq0 = *(const bf16x8*)(base + (size_t)qrow * 2304 + h * 64 + lg * 8);
    bf16x8 aq1 = *(const bf16x8*)(base + (size_t)qrow * 2304 + h * 64 + 32 + lg * 8);
    __syncthreads();

    f32x4 s[KT];
    const int sw = (l15 & 7) << 4;
#pragma unroll
    for (int t = 0; t < KT; ++t) {
        const char* krow = (const char*)lds0 + (t * 16 + l15) * 128;
        bf16x8 bk0 = *(const bf16x8*)(krow + ((lg * 16) ^ sw));
        bf16x8 bk1 = *(const bf16x8*)(krow + ((64 + lg * 16) ^ sw));
        f32x4 acc = {};
        acc = __builtin_amdgcn_mfma_f32_16x16x32_bf16(aq0, bk0, acc, 0, 0, 0);
        acc = __builtin_amdgcn_mfma_f32_16x16x32_bf16(aq1, bk1, acc, 0, 0, 0);
        s[t] = acc * 0.125f;
    }
    float mx[4] = {-1e30f, -1e30f, -1e30f, -1e30f};
#pragma unroll
    for (int t = 0; t < KT; ++t)
#pragma unroll
        for (int r = 0; r < 4; ++r) mx[r] = fmaxf(mx[r], s[t][r]);
#pragma unroll
    for (int off = 1; off < 16; off <<= 1)
#pragma unroll
        for (int r = 0; r < 4; ++r) mx[r] = fmaxf(mx[r], __shfl_xor(mx[r], off));
    float sum[4] = {};
#pragma unroll
    for (int t = 0; t < KT; ++t) {
        bool valid = (t * 16 + l15) < NGL;
#pragma unroll
        for (int r = 0; r < 4; ++r) {
            float e = valid ? __expf(s[t][r] - mx[r]) : 0.f;
            s[t][r] = e;
            sum[r] += e;
        }
    }
#pragma unroll
    for (int off = 1; off < 16; off <<= 1)
#pragma unroll
        for (int r = 0; r < 4; ++r) sum[r] += __shfl_xor(sum[r], off);
    float inv[4];
#pragma unroll
    for (int r = 0; r < 4; ++r) inv[r] = 1.f / sum[r];

    __syncthreads();
    u16* Pw = lds0 + wv * 16 * PS_STRIDE;
#pragma unroll
    for (int t = 0; t < KT; ++t)
#pragma unroll
        for (int r = 0; r < 4; ++r)
            Pw[(4 * lg + r) * PS_STRIDE + t * 16 + l15] = f2bf(s[t][r] * inv[r]);

    f32x4 o[4] = {};
#pragma unroll
    for (int ks = 0; ks < 7; ++ks) {
        bf16x8 pa = *(const bf16x8*)(Pw + l15 * PS_STRIDE + ks * 32 + lg * 8);
#pragma unroll
        for (int dt = 0; dt < 4; ++dt) {
            bf16x8 bv = *(const bf16x8*)((const char*)Vt + (size_t)(dt * 16 + l15) * (VT_STRIDE * 2) + ks * 64 + lg * 16);
            o[dt] = __builtin_amdgcn_mfma_f32_16x16x32_bf16(pa, bv, o[dt], 0, 0, 0);
        }
    }
#pragma unroll
    for (int dt = 0; dt < 4; ++dt)
#pragma unroll
        for (int r = 0; r < 4; ++r) {
            int q = q0 + 4 * lg + r;
            if (q < NGL) Z[((size_t)b * NT + q) * CDIM + h * 64 + dt * 16 + l15] = f2bf(o[dt][r]);
        }
}

// ---------------- Neighborhood attention ----------------
__global__ __launch_bounds__(64) void attn_neigh(const u16* __restrict__ qkv, const float* __restrict__ ps,
                                                 u16* __restrict__ Z) {
    int blk = blockIdx.x;
    int b = blk >> 6, m = blk & 63;
    int lane = threadIdx.x;
    float px = ps[((size_t)b * 64 + m) * 2 + 0] * (1.f / 16.f);
    float py = ps[((size_t)b * 64 + m) * 2 + 1] * (1.f / 16.f);
    int c0 = min(max((int)floorf(px), 0), 13);
    int c1 = min(max((int)ceilf(px), 0), 13);
    int r0 = min(max((int)floorf(py), 0), 13);
    int r1 = min(max((int)ceilf(py), 0), 13);
    int tok[4];
    tok[0] = 1 + r0 * 14 + c0;
    tok[1] = 1 + r1 * 14 + c0;
    tok[2] = 1 + r0 * 14 + c1;
    tok[3] = 1 + r1 * 14 + c1;
    const size_t rowq = ((size_t)b * NT + NGL + m) * 2304;
#pragma unroll 1
    for (int h = 0; h < NHEAD; ++h) {
        float qv = bf2f(qkv[rowq + h * 64 + lane]);
        float a[4];
#pragma unroll
        for (int j = 0; j < 4; ++j) {
            float p = qv * bf2f(qkv[((size_t)b * NT + tok[j]) * 2304 + 768 + h * 64 + lane]);
#pragma unroll
            for (int off = 32; off; off >>= 1) p += __shfl_xor(p, off);
            a[j] = p;
        }
        float mx = fmaxf(fmaxf(a[0], a[1]), fmaxf(a[2], a[3]));
        float e0 = expf(a[0] - mx), e1 = expf(a[1] - mx), e2 = expf(a[2] - mx), e3 = expf(a[3] - mx);
        float inv = 1.f / (e0 + e1 + e2 + e3);
        float v0 = bf2f(qkv[((size_t)b * NT + tok[0]) * 2304 + 1536 + h * 64 + lane]);
        float v1 = bf2f(qkv[((size_t)b * NT + tok[1]) * 2304 + 1536 + h * 64 + lane]);
        float v2 = bf2f(qkv[((size_t)b * NT + tok[2]) * 2304 + 1536 + h * 64 + lane]);
        float v3 = bf2f(qkv[((size_t)b * NT + tok[3]) * 2304 + 1536 + h * 64 + lane]);
        float o = (e0 * v0 + e1 * v1 + e2 * v2 + e3 * v3) * inv;
        Z[((size_t)b * NT + NGL + m) * CDIM + h * 64 + lane] = f2bf(o);
    }
}

extern "C" void kernel_launch(void* const* d_in, const int* in_sizes, int n_in,
                              void* d_out, int out_size, void* d_ws, size_t ws_size,
                              hipStream_t stream) {
    const float* x      = (const float*)d_in[0];
    const float* ps     = (const float*)d_in[1];
    const float* n1w    = (const float*)d_in[3];
    const float* n1b    = (const float*)d_in[4];
    const float* qkv_w  = (const float*)d_in[5];
    const float* proj_w = (const float*)d_in[6];
    const float* proj_b = (const float*)d_in[7];
    const float* n2w    = (const float*)d_in[8];
    const float* n2b    = (const float*)d_in[9];
    const float* fc1_w  = (const float*)d_in[10];
    const float* fc1_b  = (const float*)d_in[11];
    const float* fc2_w  = (const float*)d_in[12];
    const float* fc2_b  = (const float*)d_in[13];

    char* ws = (char*)d_ws;
    const int M = 32 * NT;  // 8352
    u16* hbuf  = (u16*)ws;                               // 12,828,672 B
    u16* qkvb  = (u16*)(ws + 12828672);                  // 38,486,016 B
    u16* Zb    = (u16*)(ws + 12828672 + 38486016);       // 12,828,672 B
    u16* Gb    = (u16*)(ws + 12828672);                  // 51,314,688 B (aliases qkv+Z, both dead)
    float* x1  = (float*)(ws + 64143360);                // 25,657,344 B
    u16* wq    = (u16*)(ws + 89800704);
    u16* wp    = wq + 2304 * 768;
    u16* w1    = wp + 768 * 768;
    u16* w2    = w1 + 3072 * 768;

    convk<<<(2304 * 768 / 4 + 255) / 256, 256, 0, stream>>>(qkv_w, wq, 2304 * 768 / 4);
    convk<<<(768 * 768 / 4 + 255) / 256, 256, 0, stream>>>(proj_w, wp, 768 * 768 / 4);
    convk<<<(3072 * 768 / 4 + 255) / 256, 256, 0, stream>>>(fc1_w, w1, 3072 * 768 / 4);
    convk<<<(768 * 3072 / 4 + 255) / 256, 256, 0, stream>>>(fc2_w, w2, 768 * 3072 / 4);

    ln_k<<<M, 256, 0, stream>>>(x, n1w, n1b, hbuf);
    gemm2<0><<<66 * 18, 256, 0, stream>>>(hbuf, wq, M, 2304, 768, 18, nullptr, nullptr, qkvb);
    attn_global_mfma<<<32 * NHEAD * 4, 256, 0, stream>>>(qkvb, Zb);
    attn_neigh<<<32 * 64, 64, 0, stream>>>(qkvb, ps, Zb);
    gemm2<1><<<66 * 6, 256, 0, stream>>>(Zb, wp, M, 768, 768, 6, proj_b, x, x1);
    ln_k<<<M, 256, 0, stream>>>(x1, n2w, n2b, hbuf);
    gemm2<2><<<66 * 24, 256, 0, stream>>>(hbuf, w1, M, 3072, 768, 24, fc1_b, nullptr, Gb);
    gemm2<1><<<66 * 6, 256, 0, stream>>>(Gb, w2, M, 768, 3072, 6, fc2_b, x1, (float*)d_out);
}